// Round 9
// baseline (865.319 us; speedup 1.0000x reference)
//
#include <hip/hip_runtime.h>
#include <hip/hip_cooperative_groups.h>
namespace cg = cooperative_groups;

typedef __bf16 bf16_t;
typedef __attribute__((ext_vector_type(8))) __bf16 bf16x8;
typedef __attribute__((ext_vector_type(4))) float f32x4;
typedef __attribute__((ext_vector_type(8))) unsigned short u16x8;

// async global->LDS DMA, 16B per lane; LDS dst linear in lane (base + lane*16)
__device__ __forceinline__ void dma16(const void* g, void* l) {
    __builtin_amdgcn_global_load_lds(
        reinterpret_cast<const unsigned int __attribute__((address_space(1)))*>(
            reinterpret_cast<unsigned long long>(g)),
        reinterpret_cast<unsigned int __attribute__((address_space(3)))*>(
            (unsigned int)reinterpret_cast<unsigned long long>(l)),
        16, 0, 0);
}

__device__ __forceinline__ float ldparam(const void* p, int i, int isbf) {
    return isbf ? (float)((const bf16_t*)p)[i] : ((const float*)p)[i];
}

// ---------------- GEMM1 phase: A[rows x K] @ W1 -> GELU(+opbias) -> H  (BM=128,BN=128,BK=32)
__device__ void gemm1_phase(char* U,
    const int* list_t, const int* list_b, const int* cntp, const int* lvl_idx,
    const int* op_ids, const bf16_t* At, const bf16_t* Ab,
    const bf16_t* W1tf, const bf16_t* W1bf,
    const float* obt, const float* obb, bf16_t* H)
{
    unsigned short* Ash = (unsigned short*)U;           // [128][32]
    unsigned short* Bsh = (unsigned short*)(U + 8192);  // [128][32]
    int* opRowL = (int*)(U + 16384);                    // [128]
    const int tid = threadIdx.x;
    const int cnt_t = cntp[1], cnt_b = cntp[0];
    const int nbt = (cnt_t + 127) >> 7, nbb = (cnt_b + 127) >> 7;
    const int ntiles = (nbt + nbb) * 4;
    const int w = tid >> 6, lane = tid & 63, cc = lane & 15, qq = lane >> 4;
    const int wm = w >> 1, wn = w & 1;

    for (int t = blockIdx.x; t < ntiles; t += gridDim.x) {
        const int cb0 = t >> 2, Nb = t & 3;
        int Mb, cnt, K, Kc;
        const int* list; const bf16_t *Ar, *Wf; const float* obp; bf16_t* Hp;
        if (cb0 < nbt) {
            list = list_t; Mb = cb0 << 7; cnt = cnt_t; K = 768; Kc = 24;
            Ar = At; Wf = W1tf; obp = obt; Hp = H;
        } else {
            int cb = cb0 - nbt; Mb = cb << 7; cnt = cnt_b; K = 512; Kc = 16;
            list = list_b; Ar = Ab; Wf = W1bf; obp = obb; Hp = H + (size_t)16384 * 512;
        }
        const int act = min(128, cnt - Mb);
        __syncthreads();   // protect U reuse across tiles
        if (tid < 128) opRowL[tid] = op_ids[lvl_idx[list[Mb + min(tid, act - 1)]]];

        const f32x4 zf = {0.f, 0.f, 0.f, 0.f};
        f32x4 acc[4][4];
#pragma unroll
        for (int mi = 0; mi < 4; mi++) for (int ji = 0; ji < 4; ji++) acc[mi][ji] = zf;

        for (int kc = 0; kc < Kc; kc++) {
            __syncthreads();
#pragma unroll
            for (int s = 0; s < 2; s++) {
                int idx = s * 256 + tid;
                int row = idx >> 2, c4 = idx & 3;
                dma16(Ar + (size_t)(Mb + row) * K + kc * 32 + c4 * 8, (char*)Ash + idx * 16);
                dma16(Wf + ((size_t)kc * 512 + (Nb << 7) + row) * 32 + c4 * 8, (char*)Bsh + idx * 16);
            }
            __syncthreads();
            bf16x8 af[4], bfv[4];
#pragma unroll
            for (int mi = 0; mi < 4; mi++)
                af[mi] = *(const bf16x8*)((const bf16_t*)Ash + (wm * 64 + mi * 16 + cc) * 32 + qq * 8);
#pragma unroll
            for (int ji = 0; ji < 4; ji++)
                bfv[ji] = *(const bf16x8*)((const bf16_t*)Bsh + (wn * 64 + ji * 16 + cc) * 32 + qq * 8);
#pragma unroll
            for (int ji = 0; ji < 4; ji++)
#pragma unroll
                for (int mi = 0; mi < 4; mi++)
                    acc[mi][ji] = __builtin_amdgcn_mfma_f32_16x16x32_bf16(af[mi], bfv[ji], acc[mi][ji], 0, 0, 0);
        }
        __syncthreads();   // opRowL reads below vs next-tile writes
#pragma unroll
        for (int ji = 0; ji < 4; ji++) {
            int col = (Nb << 7) + wn * 64 + ji * 16 + cc;
#pragma unroll
            for (int mi = 0; mi < 4; mi++) for (int r = 0; r < 4; r++) {
                int row = wm * 64 + mi * 16 + qq * 4 + r;
                float v = acc[mi][ji][r] + obp[opRowL[row] * 512 + col];
                float h = 0.5f * v * (1.0f + erff(v * 0.70710678118654752f));
                Hp[(size_t)(Mb + row) * 512 + col] = (bf16_t)h;
            }
        }
    }
}

// ---------------- GEMM2 phase: H @ W2 + b2 + residual -> LN -> write-through/out (BM=64,BN=256)
__device__ void gemm2_phase(char* U, int isbf,
    const int* list_t, const int* list_b, const int* cntp, const int* lvl_idx,
    const unsigned* par, const bf16_t* At, const bf16_t* Ab,
    const bf16_t* W2tf, const bf16_t* W2bf,
    const void* b2t_, const void* b2b_, const void* gma, const void* bta,
    const bf16_t* H, bf16_t* Ant, bf16_t* Anb, void* outp)
{
    unsigned short* Ash = (unsigned short*)U;            // [64][32]
    unsigned short* Bsh = (unsigned short*)(U + 4096);   // [256][32]
    float* Rf    = (float*)U;                            // [64][260]
    float* partS = (float*)(U + 66560);
    float* partQ = (float*)(U + 67584);
    float* muA   = (float*)(U + 68608);
    float* rsA   = (float*)(U + 68864);
    int*   lrA   = (int*)(U + 69120);
    unsigned* parA = (unsigned*)(U + 69376);

    const int tid = threadIdx.x;
    const int cnt_t = cntp[1], cnt_b = cntp[0];
    const int nbt = (cnt_t + 63) >> 6, nbb = (cnt_b + 63) >> 6;
    const int ntiles = nbt + nbb;
    const int w = tid >> 6, lane = tid & 63, cc = lane & 15, qq = lane >> 4;

    for (int t = blockIdx.x; t < ntiles; t += gridDim.x) {
        int tern, Mb, cnt, K;
        const int* list; const bf16_t *Ar, *Wf, *Hsrc; const void* b2;
        if (t < nbt) {
            tern = 1; list = list_t; Mb = t << 6; cnt = cnt_t; K = 768;
            Ar = At; Wf = W2tf; b2 = b2t_; Hsrc = H;
        } else {
            int cb = t - nbt; Mb = cb << 6; cnt = cnt_b; K = 512;
            tern = 0; list = list_b; Ar = Ab; Wf = W2bf; b2 = b2b_;
            Hsrc = H + (size_t)16384 * 512;
        }
        const int act = min(64, cnt - Mb);
        __syncthreads();   // protect U reuse across tiles
        if (tid < 64) {
            int lr = list[Mb + min(tid, act - 1)];
            lrA[tid] = lr;
            parA[tid] = outp ? 0u : par[lvl_idx[lr]];
        }

        const f32x4 zf = {0.f, 0.f, 0.f, 0.f};
        f32x4 acc[4][4];
#pragma unroll
        for (int mi = 0; mi < 4; mi++) for (int ji = 0; ji < 4; ji++) acc[mi][ji] = zf;

        for (int kc = 0; kc < 16; kc++) {
            __syncthreads();
            {
                int row = tid >> 2, c4 = tid & 3;
                dma16(Hsrc + (size_t)(Mb + row) * 512 + kc * 32 + c4 * 8, (char*)Ash + tid * 16);
            }
#pragma unroll
            for (int s = 0; s < 4; s++) {
                int idx = s * 256 + tid;
                int n = idx >> 2, c4 = idx & 3;
                dma16(Wf + ((size_t)kc * 256 + n) * 32 + c4 * 8, (char*)Bsh + idx * 16);
            }
            __syncthreads();
            bf16x8 af[4], bfv[4];
#pragma unroll
            for (int mi = 0; mi < 4; mi++)
                af[mi] = *(const bf16x8*)((const bf16_t*)Ash + (mi * 16 + cc) * 32 + qq * 8);
#pragma unroll
            for (int ji = 0; ji < 4; ji++)
                bfv[ji] = *(const bf16x8*)((const bf16_t*)Bsh + (w * 64 + ji * 16 + cc) * 32 + qq * 8);
#pragma unroll
            for (int ji = 0; ji < 4; ji++)
#pragma unroll
                for (int mi = 0; mi < 4; mi++)
                    acc[mi][ji] = __builtin_amdgcn_mfma_f32_16x16x32_bf16(af[mi], bfv[ji], acc[mi][ji], 0, 0, 0);
        }
        __syncthreads();

        // residual from this level's contiguous A-rows
        {
            int rr = tid >> 2, q4 = tid & 3;
            int rmin = min(rr, act - 1);
            const bf16_t* base = Ar + (size_t)(Mb + rmin) * K;
            float scale = tern ? (1.0f / 3.0f) : 1.0f;
            for (int j = 0; j < 8; j++) {
                int q = q4 * 64 + j * 8;
                bf16x8 a = *(const bf16x8*)(base + q);
                bf16x8 b = *(const bf16x8*)(base + 256 + q);
                float s[8];
                for (int z = 0; z < 8; z++) s[z] = (float)a[z] + (float)b[z];
                if (tern) {
                    bf16x8 c = *(const bf16x8*)(base + 512 + q);
                    for (int z = 0; z < 8; z++) s[z] += (float)c[z];
                }
                f32x4 o0, o1;
                for (int z = 0; z < 4; z++) { o0[z] = s[z] * scale; o1[z] = s[z + 4] * scale; }
                *(f32x4*)(Rf + rr * 260 + q) = o0;
                *(f32x4*)(Rf + rr * 260 + q + 4) = o1;
            }
        }
        __syncthreads();

        float b2f[4], gf[4], btf[4];
#pragma unroll
        for (int ji = 0; ji < 4; ji++) {
            int col = w * 64 + ji * 16 + cc;
            b2f[ji] = ldparam(b2, col, isbf);
            gf[ji] = ldparam(gma, col, isbf);
            btf[ji] = ldparam(bta, col, isbf);
        }
#pragma unroll
        for (int mi = 0; mi < 4; mi++) for (int r = 0; r < 4; r++) {
            int row = mi * 16 + qq * 4 + r;
            float ps = 0.f, pq = 0.f;
#pragma unroll
            for (int ji = 0; ji < 4; ji++) {
                int col = w * 64 + ji * 16 + cc;
                float x = acc[mi][ji][r] + b2f[ji] + Rf[row * 260 + col];
                acc[mi][ji][r] = x;
                ps += x; pq += x * x;
            }
            for (int d = 1; d < 16; d <<= 1) {
                ps += __shfl_xor(ps, d, 64);
                pq += __shfl_xor(pq, d, 64);
            }
            if (cc == 0) { partS[w * 64 + row] = ps; partQ[w * 64 + row] = pq; }
        }
        __syncthreads();
        if (tid < 64) {
            float s  = partS[tid] + partS[64 + tid] + partS[128 + tid] + partS[192 + tid];
            float sq = partQ[tid] + partQ[64 + tid] + partQ[128 + tid] + partQ[192 + tid];
            float mu = s * (1.0f / 256.0f);
            float var = sq * (1.0f / 256.0f) - mu * mu;
            muA[tid] = mu;
            rsA[tid] = rsqrtf(fmaxf(var, 0.0f) + 1e-5f);
        }
        __syncthreads();

#pragma unroll
        for (int mi = 0; mi < 4; mi++) for (int r = 0; r < 4; r++) {
            int row = mi * 16 + qq * 4 + r;
            if (row >= act) continue;
            float mu = muA[row], rs = rsA[row];
#pragma unroll
            for (int ji = 0; ji < 4; ji++) {
                int col = w * 64 + ji * 16 + cc;
                float y = (acc[mi][ji][r] - mu) * rs * gf[ji] + btf[ji];
                if (outp) {
                    size_t o = (size_t)lrA[row] * 256 + col;
                    if (isbf) ((bf16_t*)outp)[o] = (bf16_t)y;
                    else      ((float*)outp)[o] = y;
                } else {
                    unsigned pr = parA[row];
                    int bkt = pr >> 31, prow = (pr >> 2) & 0x3FFF, pc = pr & 3;
                    bf16_t* dst = bkt ? Ant : Anb;
                    int Kn = bkt ? 768 : 512;
                    dst[(size_t)prow * Kn + pc * 256 + col] = (bf16_t)y;
                }
            }
        }
    }
}

// ---------------- the cooperative mega-kernel: 1 dispatch, 8 grid syncs
__global__ __launch_bounds__(256, 2) void mega(
    const int* __restrict__ cid, const int* __restrict__ opids,
    const int* __restrict__ lch, const int* __restrict__ rch, const int* __restrict__ tch,
    const int* __restrict__ lvl2, const int* __restrict__ lvl1, const int* __restrict__ lvl0,
    const void* __restrict__ ct, const void* __restrict__ opt,
    const void* __restrict__ W1b_, const void* __restrict__ b1b_,
    const void* __restrict__ W2b_, const void* __restrict__ b2b_,
    const void* __restrict__ W1t_, const void* __restrict__ b1t_,
    const void* __restrict__ W2t_, const void* __restrict__ b2t_,
    const void* __restrict__ gma, const void* __restrict__ bta,
    char* __restrict__ ws, void* __restrict__ outp)
{
    cg::grid_group grid = cg::this_grid();
    __shared__ __align__(16) char U[69632];
    __shared__ int shIsbf;

    // ws layout
    bf16_t* A2t  = (bf16_t*)ws;
    bf16_t* A2b  = (bf16_t*)(ws + 25165824);
    bf16_t* A1t  = (bf16_t*)(ws + 41943040);
    bf16_t* A1b  = (bf16_t*)(ws + 54525952);
    bf16_t* A0t  = (bf16_t*)(ws + 62914560);
    bf16_t* A0b  = (bf16_t*)(ws + 69206016);
    bf16_t* H    = (bf16_t*)(ws + 73400320);
    bf16_t* W1tf = (bf16_t*)(ws + 106954752);
    bf16_t* W1bf = (bf16_t*)(ws + 107741184);
    bf16_t* W2tf = (bf16_t*)(ws + 108265472);
    bf16_t* W2bf = (bf16_t*)(ws + 108527616);
    float*  obt  = (float*)(ws + 108789760);
    float*  obb  = (float*)(ws + 108822528);
    int*    lists = (int*)(ws + 108855296);
    unsigned* par = (unsigned*)(ws + 109084672);
    int*    cnts  = (int*)(ws + 109346816);

    const int tid = threadIdx.x;
    if (tid == 0) {
        const unsigned short* cw = (const unsigned short*)ct;
        int ok = 1;
        for (int i = 0; i < 16; i++) {
            int e = (cw[256 + i] >> 7) & 0xFF;
            ok &= (e >= 80 && e <= 126) ? 1 : 0;
        }
        shIsbf = ok;
    }
    __syncthreads();
    const int isbf = shIsbf;
    const int gtid = blockIdx.x * 256 + tid;
    const int gsz = gridDim.x * 256;

    // ===== P0: zero cnts + pack weights + opbias =====
    if (gtid < 16) cnts[gtid] = 0;
    for (int g = gtid; g < 16384; g += gsz) {           // opbias: one thread per output
        int col = g & 511, ro = g >> 9;
        int typ = ro >> 4, o = ro & 15;
        const void* W = typ ? W1t_ : W1b_;
        const void* bb = typ ? b1t_ : b1b_;
        float* ob = typ ? obt : obb;
        float a = 0.f;
        for (int k = 0; k < 256; k++)
            a += ldparam(opt, o * 256 + k, isbf) * ldparam(W, k * 512 + col, isbf);
        ob[o * 512 + col] = a + ldparam(bb, col, isbf);
    }
    for (int e = gtid; e < 917504; e += gsz) {          // pack children-rows of W1/W2
        if (e < 393216) {
            int k = e >> 9, n = e & 511, si = (k + 256) * 512 + n;
            bf16_t v = isbf ? ((const bf16_t*)W1t_)[si] : (bf16_t)((const float*)W1t_)[si];
            W1tf[(size_t)(((k >> 5) * 512 + n) * 32 + (k & 31))] = v;
        } else if (e < 655360) {
            int e2 = e - 393216, k = e2 >> 9, n = e2 & 511, si = (k + 256) * 512 + n;
            bf16_t v = isbf ? ((const bf16_t*)W1b_)[si] : (bf16_t)((const float*)W1b_)[si];
            W1bf[(size_t)(((k >> 5) * 512 + n) * 32 + (k & 31))] = v;
        } else if (e < 786432) {
            int e2 = e - 655360, k = e2 >> 8, n = e2 & 255, si = k * 256 + n;
            bf16_t v = isbf ? ((const bf16_t*)W2t_)[si] : (bf16_t)((const float*)W2t_)[si];
            W2tf[(size_t)(((k >> 5) * 256 + n) * 32 + (k & 31))] = v;
        } else {
            int e2 = e - 786432, k = e2 >> 8, n = e2 & 255, si = k * 256 + n;
            bf16_t v = isbf ? ((const bf16_t*)W2b_)[si] : (bf16_t)((const float*)W2b_)[si];
            W2bf[(size_t)(((k >> 5) * 256 + n) * 32 + (k & 31))] = v;
        }
    }
    __threadfence(); grid.sync();

    // ===== P1: scan (wave-aggregated partition + parent map) =====
    for (int r = gtid; r < 28672; r += gsz) {
        int slot, lr, base_t, base_b;
        const int* lvl;
        if (r < 16384)      { slot = 0; lr = r;         lvl = lvl2; base_t = 0;     base_b = 16384; }
        else if (r < 24576) { slot = 1; lr = r - 16384; lvl = lvl1; base_t = 32768; base_b = 40960; }
        else                { slot = 2; lr = r - 24576; lvl = lvl0; base_t = 49152; base_b = 53248; }
        int node = lvl[lr];
        int tern = tch[node] >= 0 ? 1 : 0;
        unsigned long long bt = __ballot(tern);
        unsigned long long bb = __ballot(!tern);
        int lane = tid & 63;
        unsigned long long ltm = (1ull << lane) - 1ull;
        int post = __popcll(bt & ltm), posb = __popcll(bb & ltm);
        int baseT = 0, baseB = 0;
        if (lane == 0) {
            baseT = atomicAdd(&cnts[slot * 2 + 1], __popcll(bt));
            baseB = atomicAdd(&cnts[slot * 2 + 0], __popcll(bb));
        }
        baseT = __shfl(baseT, 0, 64);
        baseB = __shfl(baseB, 0, 64);
        int idx_in = tern ? (baseT + post) : (baseB + posb);
        lists[(tern ? base_t : base_b) + idx_in] = lr;
        if (slot >= 1) {
            unsigned enc = ((unsigned)tern << 31) | ((unsigned)idx_in << 2);
            par[lch[node]] = enc | 0u;
            par[rch[node]] = enc | 1u;
            if (tern) par[tch[node]] = enc | 2u;
        }
    }
    __threadfence(); grid.sync();

    // ===== P2: leaf gather -> lvl2 A-rows =====
    {
        int cnt_t2 = cnts[1], cnt_b2 = cnts[0];
        int tot_t = cnt_t2 * 96, tot_b = cnt_b2 * 64;
        for (int e = gtid; e < tot_t + tot_b; e += gsz) {
            int row, ch, K;
            const int* list; bf16_t* dst;
            int e2;
            if (e < tot_t) { row = e / 96; ch = e - row * 96; list = lists; dst = A2t; K = 768; }
            else { e2 = e - tot_t; row = e2 >> 6; ch = e2 & 63; list = lists + 16384; dst = A2b; K = 512; }
            int nd = lvl2[list[row]];
            int colg = ch * 8, piece = colg >> 8, po = colg & 255;
            int child = piece == 0 ? lch[nd] : (piece == 1 ? rch[nd] : tch[nd]);
            int cp = cid[child];
            bf16_t* d = dst + (size_t)row * K + colg;
            if (isbf) {
                *(u16x8*)d = *(const u16x8*)((const unsigned short*)ct + (size_t)cp * 256 + po);
            } else {
                const float* fp = (const float*)ct + (size_t)cp * 256 + po;
                bf16_t t8[8];
                for (int z = 0; z < 8; z++) t8[z] = (bf16_t)fp[z];
                *(u16x8*)d = *(u16x8*)t8;
            }
        }
    }
    __threadfence(); grid.sync();

    // ===== P3..P8: three levels of gemm1 / gemm2 =====
    const int* Lidx[3] = {lvl2, lvl1, lvl0};
    const int* lt[3] = {lists, lists + 32768, lists + 49152};
    const int* lb[3] = {lists + 16384, lists + 40960, lists + 53248};
    const int* cp3[3] = {cnts, cnts + 2, cnts + 4};
    const bf16_t* Ats[3] = {A2t, A1t, A0t};
    const bf16_t* Abs[3] = {A2b, A1b, A0b};
    bf16_t* Ant[3] = {A1t, A0t, nullptr};
    bf16_t* Anb[3] = {A1b, A0b, nullptr};
    void* outs[3] = {nullptr, nullptr, outp};

    for (int L = 0; L < 3; L++) {
        gemm1_phase(U, lt[L], lb[L], cp3[L], Lidx[L], opids,
                    Ats[L], Abs[L], W1tf, W1bf, obt, obb, H);
        __threadfence(); grid.sync();
        gemm2_phase(U, isbf, lt[L], lb[L], cp3[L], Lidx[L], par,
                    Ats[L], Abs[L], W2tf, W2bf, b2t_, b2b_, gma, bta,
                    H, Ant[L], Anb[L], outs[L]);
        if (L < 2) { __threadfence(); grid.sync(); }
    }
}

extern "C" void kernel_launch(void* const* d_in, const int* in_sizes, int n_in,
                              void* d_out, int out_size, void* d_ws, size_t ws_size,
                              hipStream_t stream) {
    const int* cid    = (const int*)d_in[0];
    const int* opids  = (const int*)d_in[1];
    const int* lch    = (const int*)d_in[2];
    const int* rch    = (const int*)d_in[3];
    const int* tch    = (const int*)d_in[4];
    const int* lvl2   = (const int*)d_in[5];
    const int* lvl1   = (const int*)d_in[6];
    const int* lvl0   = (const int*)d_in[7];
    const void* ct  = d_in[8];
    const void* opt = d_in[9];
    const void* W1b_ = d_in[10];
    const void* b1b_ = d_in[11];
    const void* W2b_ = d_in[12];
    const void* b2b_ = d_in[13];
    const void* W1t_ = d_in[14];
    const void* b1t_ = d_in[15];
    const void* W2t_ = d_in[16];
    const void* b2t_ = d_in[17];
    const void* gma = d_in[18];
    const void* bta = d_in[19];
    char* ws = (char*)d_ws;
    void* outp = d_out;

    int nb = 0;
    hipError_t qe = hipOccupancyMaxActiveBlocksPerMultiprocessor(&nb, mega, 256, 0);
    int grid = (qe == hipSuccess && nb >= 2) ? 512 : 256;

    void* args[] = {
        (void*)&cid, (void*)&opids, (void*)&lch, (void*)&rch, (void*)&tch,
        (void*)&lvl2, (void*)&lvl1, (void*)&lvl0,
        (void*)&ct, (void*)&opt,
        (void*)&W1b_, (void*)&b1b_, (void*)&W2b_, (void*)&b2b_,
        (void*)&W1t_, (void*)&b1t_, (void*)&W2t_, (void*)&b2t_,
        (void*)&gma, (void*)&bta,
        (void*)&ws, (void*)&outp
    };
    hipLaunchCooperativeKernel(mega, dim3(grid), dim3(256), args, 0, stream);
}